// Round 14
// baseline (168.726 us; speedup 1.0000x reference)
//
#include <hip/hip_runtime.h>

typedef __attribute__((ext_vector_type(8))) _Float16 f16x8;
typedef __attribute__((ext_vector_type(4))) float   f32x4;

namespace {
constexpr int kB    = 8192;
constexpr int kTH   = 11;
constexpr int kTP   = 80;
constexpr int kM    = 16;    // batch rows per block (MFMA M)
constexpr int kStrH = 72;    // H-plane row stride in fp16 units (144 B: 16B-aligned)
}

__device__ __forceinline__ f16x8 zero_frag() {
    f16x8 z = {0, 0, 0, 0, 0, 0, 0, 0};
    return z;
}

// 8 fp32 -> single fp16x8 (round-to-nearest)
__device__ __forceinline__ f16x8 cvt8(const float* f) {
    f16x8 v;
#pragma unroll
    for (int j = 0; j < 8; ++j) v[j] = (_Float16)f[j];
    return v;
}

// B-fragment (single fp16) for column `col`: B[k][col] = W[col][k].
__device__ __forceinline__ void loadB1(const float* __restrict__ W, int col, int q,
                                       f16x8 (&Bf)[2]) {
#pragma unroll
    for (int c = 0; c < 2; ++c) {
        const float* src = W + col * 64 + c * 32 + q * 8;
        const float4 a = reinterpret_cast<const float4*>(src)[0];
        const float4 b = reinterpret_cast<const float4*>(src)[1];
        float f[8] = {a.x, a.y, a.z, a.w, b.x, b.y, b.z, b.w};
        Bf[c] = cvt8(f);
    }
}

// fc B-fragment: only cols p<2 are real (fcW is 2x64); others zero.
__device__ __forceinline__ void loadBfc(const float* __restrict__ fcW, int p, int q,
                                        f16x8 (&Bf)[2]) {
#pragma unroll
    for (int c = 0; c < 2; ++c) {
        float f[8];
#pragma unroll
        for (int j = 0; j < 8; ++j)
            f[j] = (p < 2) ? fcW[p * 64 + c * 32 + q * 8 + j] : 0.f;
        Bf[c] = cvt8(f);
    }
}

// G = w0 (x) fcW[0] + w1 (x) fcW[1]  (rank-2 folded feedback matrix)
__device__ __forceinline__ void loadBG(const float* __restrict__ fcW, float w0, float w1,
                                       int q, f16x8 (&Bf)[2]) {
#pragma unroll
    for (int c = 0; c < 2; ++c) {
        float f[8];
#pragma unroll
        for (int j = 0; j < 8; ++j) {
            const int k = c * 32 + q * 8 + j;
            f[j] = w0 * fcW[k] + w1 * fcW[64 + k];
        }
        Bf[c] = cvt8(f);
    }
}

// split h into fp16 hi + fp16 lo (lo = remainder) and store to planes
__device__ __forceinline__ void write_h(_Float16* hi, _Float16* lo, int idx, float h) {
    const _Float16 hh = (_Float16)h;
    const _Float16 hl = (_Float16)(h - (float)hh);
    hi[idx] = hh;
    lo[idx] = hl;
}

__device__ __forceinline__ f16x8 read_frag(const _Float16* plane, int off) {
    return *reinterpret_cast<const f16x8*>(plane + off);
}

// 2-term accumulate: D += Ah*B + Al*B  (A = fp16 hi/lo, B = single fp16)
__device__ __forceinline__ f32x4 mfma2(f16x8 ah, f16x8 al, f16x8 b, f32x4 acc) {
    acc = __builtin_amdgcn_mfma_f32_16x16x32_f16(ah, b, acc, 0, 0, 0);
    acc = __builtin_amdgcn_mfma_f32_16x16x32_f16(al, b, acc, 0, 0, 0);
    return acc;
}

// tanh via raw v_exp/v_rcp: 1 - 2*rcp(2^(2*log2e*x)+1); saturates safely.
__device__ __forceinline__ float fast_tanh(float x) {
    const float e = __builtin_amdgcn_exp2f(x * 2.8853900817779268f);  // 2/ln2
    return fmaf(-2.0f, __builtin_amdgcn_rcpf(e + 1.0f), 1.0f);
}

// R9 structure: 512 blocks x 4 waves (n-split), 2 waves/SIMD grid-limited.
__global__ __attribute__((amdgpu_waves_per_eu(2, 2))) __launch_bounds__(256)
void traj_rnn_kernel(
    const float* __restrict__ x,
    const float* __restrict__ eWih0, const float* __restrict__ eWhh0,
    const float* __restrict__ ebih0, const float* __restrict__ ebhh0,
    const float* __restrict__ eWih1, const float* __restrict__ eWhh1,
    const float* __restrict__ ebih1, const float* __restrict__ ebhh1,
    const float* __restrict__ dWih0, const float* __restrict__ dWhh0,
    const float* __restrict__ dbih0, const float* __restrict__ dbhh0,
    const float* __restrict__ dWih1, const float* __restrict__ dWhh1,
    const float* __restrict__ dbih1, const float* __restrict__ dbhh1,
    const float* __restrict__ fcW, const float* __restrict__ fcb,
    float* __restrict__ out)
{
    const int tid  = threadIdx.x;
    const int wv   = tid >> 6;          // n-tile owned by this wave (0..3)
    const int lane = tid & 63;
    const int p    = lane & 15;         // A-m / C-col-within-tile
    const int q    = lane >> 4;         // k-quad / C row-quad
    const int col  = wv * 16 + p;       // this lane's hidden-unit column
    const int r0   = blockIdx.x * kM;

    __shared__ __align__(16) _Float16 Hhi1[kM * kStrH], Hlo1[kM * kStrH];
    __shared__ __align__(16) _Float16 Hhi2[kM * kStrH], Hlo2[kM * kStrH];
    __shared__ __align__(16) float xbuf[kM * kTH * 2];
    __shared__ __align__(16) float predbuf[kM * kTP * 2];  // preds staged in LDS; flushed once

    for (int i = tid; i < kM * kTH * 2; i += 256)
        xbuf[i] = x[r0 * (kTH * 2) + i];

    f16x8 H1h[2], H1l[2], H2h[2], H2l[2];
#pragma unroll
    for (int c = 0; c < 2; ++c) {
        H1h[c] = zero_frag(); H1l[c] = zero_frag();
        H2h[c] = zero_frag(); H2l[c] = zero_frag();
    }
    __syncthreads();

    const int aoff = p * kStrH;  // A-fragment base for this lane's m-row

    // ================= encoder: 11 steps =================
    {
        const float b0 = ebih0[col] + ebhh0[col];
        const float b1 = ebih1[col] + ebhh1[col];
        const float w0 = eWih0[col * 2 + 0];
        const float w1 = eWih0[col * 2 + 1];
        f16x8 B0[2], B1[2], B2[2];
        loadB1(eWhh0, col, q, B0);   // Whh0
        loadB1(eWih1, col, q, B1);   // Wih1
        loadB1(eWhh1, col, q, B2);   // Whh1

        f32x4 P1 = {b0, b0, b0, b0};       // b0 + Whh0 . h1 (h1 = 0 initially)

#pragma unroll 1
        for (int t = 0; t < kTH; ++t) {
#pragma unroll
            for (int r = 0; r < 4; ++r) {
                const float2 xv = *reinterpret_cast<const float2*>(
                    &xbuf[(4 * q + r) * (kTH * 2) + 2 * t]);
                const float h1 = fast_tanh(fmaf(w0, xv.x, fmaf(w1, xv.y, P1[r])));
                write_h(Hhi1, Hlo1, (4 * q + r) * kStrH + col, h1);
            }
            // layer-2 partial on OLD H2 (independent of h1') before the barrier
            f32x4 a2 = {b1, b1, b1, b1};
#pragma unroll
            for (int c = 0; c < 2; ++c)
                a2 = mfma2(H2h[c], H2l[c], B2[c], a2);
            __syncthreads();   // h1' visible

            // segment A->B: keep only the chain-critical a2 finish here
#pragma unroll
            for (int c = 0; c < 2; ++c) {
                H1h[c] = read_frag(Hhi1, aoff + c * 32 + q * 8);
                H1l[c] = read_frag(Hlo1, aoff + c * 32 + q * 8);
            }
#pragma unroll
            for (int c = 0; c < 2; ++c)
                a2 = mfma2(H1h[c], H1l[c], B1[c], a2);
#pragma unroll
            for (int r = 0; r < 4; ++r) {
                const float h2 = fast_tanh(a2[r]);
                write_h(Hhi2, Hlo2, (4 * q + r) * kStrH + col, h2);
            }
            __syncthreads();   // h2' visible

            // segment B->A: next-P1 recurrent term moved here (H1 frags still live)
#pragma unroll
            for (int c = 0; c < 2; ++c) {
                H2h[c] = read_frag(Hhi2, aoff + c * 32 + q * 8);
                H2l[c] = read_frag(Hlo2, aoff + c * 32 + q * 8);
            }
            f32x4 np = {b0, b0, b0, b0};
#pragma unroll
            for (int c = 0; c < 2; ++c)
                np = mfma2(H1h[c], H1l[c], B0[c], np);
            P1 = np;
        }
    }

    // ================= decoder: 80 autoregressive steps =================
    {
        const float b0 = dbih0[col] + dbhh0[col];
        const float b1 = dbih1[col] + dbhh1[col];
        const float w0 = dWih0[col * 2 + 0];
        const float w1 = dWih0[col * 2 + 1];
        const float fb0 = fcb[0];
        const float fb1 = fcb[1];
        // folded bias: feedback constant term absorbed into layer-1 bias
        const float b0p = b0 + w0 * fb0 + w1 * fb1;
        const float fbp = (p == 0) ? fb0 : fb1;   // for LDS stash from p<2 lanes
        f16x8 B0[2], B1[2], B2[2], BF[2], BG[2];
        loadB1(dWhh0, col, q, B0);
        loadB1(dWih1, col, q, B1);
        loadB1(dWhh1, col, q, B2);
        loadBfc(fcW, p, q, BF);
        loadBG(fcW, w0, w1, q, BG);   // rank-2 folded feedback matrix

        // P1 for the FIRST decoder step: b0 + Whh0.h1_enc + w0*x_last0 + w1*x_last1
        f32x4 P1 = {b0, b0, b0, b0};
#pragma unroll
        for (int c = 0; c < 2; ++c)
            P1 = mfma2(H1h[c], H1l[c], B0[c], P1);
#pragma unroll
        for (int r = 0; r < 4; ++r) {
            const float2 xv = *reinterpret_cast<const float2*>(
                &xbuf[(4 * q + r) * (kTH * 2) + 2 * (kTH - 1)]);
            P1[r] = fmaf(w0, xv.x, fmaf(w1, xv.y, P1[r]));
        }

#pragma unroll 1
        for (int t = 0; t < kTP; ++t) {
            // layer 1: P1 is already complete (bias + recurrent + folded feedback)
#pragma unroll
            for (int r = 0; r < 4; ++r) {
                const float h1 = fast_tanh(P1[r]);
                write_h(Hhi1, Hlo1, (4 * q + r) * kStrH + col, h1);
            }
            // layer-2 partial on OLD H2 before the barrier
            f32x4 a2 = {b1, b1, b1, b1};
#pragma unroll
            for (int c = 0; c < 2; ++c)
                a2 = mfma2(H2h[c], H2l[c], B2[c], a2);
            __syncthreads();   // h1' visible

            // segment A->B: chain-critical only — finish a2, produce h2'
#pragma unroll
            for (int c = 0; c < 2; ++c) {
                H1h[c] = read_frag(Hhi1, aoff + c * 32 + q * 8);
                H1l[c] = read_frag(Hlo1, aoff + c * 32 + q * 8);
            }
#pragma unroll
            for (int c = 0; c < 2; ++c)
                a2 = mfma2(H1h[c], H1l[c], B1[c], a2);
#pragma unroll
            for (int r = 0; r < 4; ++r) {
                const float h2 = fast_tanh(a2[r]);
                write_h(Hhi2, Hlo2, (4 * q + r) * kStrH + col, h2);
            }
            __syncthreads();   // h2' visible

            // segment B->A: full next-P1 assembly (B0 term moved here) + fc
#pragma unroll
            for (int c = 0; c < 2; ++c) {
                H2h[c] = read_frag(Hhi2, aoff + c * 32 + q * 8);
                H2l[c] = read_frag(Hlo2, aoff + c * 32 + q * 8);
            }
            f32x4 np = {b0p, b0p, b0p, b0p};
#pragma unroll
            for (int c = 0; c < 2; ++c)
                np = mfma2(H2h[c], H2l[c], BG[c], np);
#pragma unroll
            for (int c = 0; c < 2; ++c)
                np = mfma2(H1h[c], H1l[c], B0[c], np);
            P1 = np;

            // pred -> LDS only (no global VMEM inside the loop; flushed after)
            if (wv == 0) {
                f32x4 fcC = {0.f, 0.f, 0.f, 0.f};
#pragma unroll
                for (int c = 0; c < 2; ++c)
                    fcC = mfma2(H2h[c], H2l[c], BF[c], fcC);
                if (p < 2) {
#pragma unroll
                    for (int r = 0; r < 4; ++r)
                        predbuf[((4 * q + r) * kTP + t) * 2 + p] = fcC[r] + fbp;
                }
            }
        }
    }

    // flush preds: block covers out[r0*kTP*2 .. (r0+16)*kTP*2), contiguous & aligned
    __syncthreads();
    {
        float4* dst = reinterpret_cast<float4*>(out + r0 * (kTP * 2));
        const float4* src = reinterpret_cast<const float4*>(predbuf);
        for (int i = tid; i < kM * kTP * 2 / 4; i += 256)
            dst[i] = src[i];
    }
}

extern "C" void kernel_launch(void* const* d_in, const int* in_sizes, int n_in,
                              void* d_out, int out_size, void* d_ws, size_t ws_size,
                              hipStream_t stream) {
    const float* x     = (const float*)d_in[0];
    const float* eWih0 = (const float*)d_in[1];
    const float* eWhh0 = (const float*)d_in[2];
    const float* ebih0 = (const float*)d_in[3];
    const float* ebhh0 = (const float*)d_in[4];
    const float* eWih1 = (const float*)d_in[5];
    const float* eWhh1 = (const float*)d_in[6];
    const float* ebih1 = (const float*)d_in[7];
    const float* ebhh1 = (const float*)d_in[8];
    const float* dWih0 = (const float*)d_in[9];
    const float* dWhh0 = (const float*)d_in[10];
    const float* dbih0 = (const float*)d_in[11];
    const float* dbhh0 = (const float*)d_in[12];
    const float* dWih1 = (const float*)d_in[13];
    const float* dWhh1 = (const float*)d_in[14];
    const float* dbih1 = (const float*)d_in[15];
    const float* dbhh1 = (const float*)d_in[16];
    const float* fcW   = (const float*)d_in[17];
    const float* fcb   = (const float*)d_in[18];
    float* out = (float*)d_out;

    dim3 grid(kB / kM);   // 512 blocks x 4 waves; wave n owns output cols 16n..16n+15
    dim3 block(256);
    traj_rnn_kernel<<<grid, block, 0, stream>>>(
        x, eWih0, eWhh0, ebih0, ebhh0, eWih1, eWhh1, ebih1, ebhh1,
        dWih0, dWhh0, dbih0, dbhh0, dWih1, dWhh1, dbih1, dbhh1,
        fcW, fcb, out);
}

// Round 15
// 141.621 us; speedup vs baseline: 1.1914x; 1.1914x over previous
//
#include <hip/hip_runtime.h>

typedef __attribute__((ext_vector_type(8))) _Float16 f16x8;
typedef __attribute__((ext_vector_type(4))) float   f32x4;

namespace {
constexpr int kB    = 8192;
constexpr int kTH   = 11;
constexpr int kTP   = 80;
constexpr int kM    = 16;    // batch rows per block (MFMA M)
constexpr int kStrH = 72;    // H-plane row stride in fp16 units (144 B: 16B-aligned)
}

// 8 fp32 -> fp16x8 (round-to-nearest)
__device__ __forceinline__ f16x8 cvt8(const float* f) {
    f16x8 v;
#pragma unroll
    for (int j = 0; j < 8; ++j) v[j] = (_Float16)f[j];
    return v;
}

// B-fragment (single fp16) for column `col`: B[k][col] = W[col][k].
__device__ __forceinline__ void loadB1(const float* __restrict__ W, int col, int q,
                                       f16x8 (&Bf)[2]) {
#pragma unroll
    for (int c = 0; c < 2; ++c) {
        const float* src = W + col * 64 + c * 32 + q * 8;
        const float4 a = reinterpret_cast<const float4*>(src)[0];
        const float4 b = reinterpret_cast<const float4*>(src)[1];
        float f[8] = {a.x, a.y, a.z, a.w, b.x, b.y, b.z, b.w};
        Bf[c] = cvt8(f);
    }
}

// fc B-fragment: only cols p<2 are real (fcW is 2x64); others zero.
__device__ __forceinline__ void loadBfc(const float* __restrict__ fcW, int p, int q,
                                        f16x8 (&Bf)[2]) {
#pragma unroll
    for (int c = 0; c < 2; ++c) {
        float f[8];
#pragma unroll
        for (int j = 0; j < 8; ++j)
            f[j] = (p < 2) ? fcW[p * 64 + c * 32 + q * 8 + j] : 0.f;
        Bf[c] = cvt8(f);
    }
}

// G = w0 (x) fcW[0] + w1 (x) fcW[1]  (rank-2 folded feedback matrix)
__device__ __forceinline__ void loadBG(const float* __restrict__ fcW, float w0, float w1,
                                       int q, f16x8 (&Bf)[2]) {
#pragma unroll
    for (int c = 0; c < 2; ++c) {
        float f[8];
#pragma unroll
        for (int j = 0; j < 8; ++j) {
            const int k = c * 32 + q * 8 + j;
            f[j] = w0 * fcW[k] + w1 * fcW[64 + k];
        }
        Bf[c] = cvt8(f);
    }
}

__device__ __forceinline__ f16x8 read_frag(const _Float16* plane, int off) {
    return *reinterpret_cast<const f16x8*>(plane + off);
}

// single-term accumulate: D += A*B (A = fp16 h, B = fp16 W)
__device__ __forceinline__ f32x4 mfma1(f16x8 a, f16x8 b, f32x4 acc) {
    return __builtin_amdgcn_mfma_f32_16x16x32_f16(a, b, acc, 0, 0, 0);
}

// tanh via raw v_exp/v_rcp: 1 - 2*rcp(2^(2*log2e*x)+1); saturates safely.
__device__ __forceinline__ float fast_tanh(float x) {
    const float e = __builtin_amdgcn_exp2f(x * 2.8853900817779268f);  // 2/ln2
    return fmaf(-2.0f, __builtin_amdgcn_rcpf(e + 1.0f), 1.0f);
}

// R9 structure: 512 blocks x 4 waves (n-split), 2 waves/SIMD grid-limited.
__global__ __attribute__((amdgpu_waves_per_eu(2, 2))) __launch_bounds__(256)
void traj_rnn_kernel(
    const float* __restrict__ x,
    const float* __restrict__ eWih0, const float* __restrict__ eWhh0,
    const float* __restrict__ ebih0, const float* __restrict__ ebhh0,
    const float* __restrict__ eWih1, const float* __restrict__ eWhh1,
    const float* __restrict__ ebih1, const float* __restrict__ ebhh1,
    const float* __restrict__ dWih0, const float* __restrict__ dWhh0,
    const float* __restrict__ dbih0, const float* __restrict__ dbhh0,
    const float* __restrict__ dWih1, const float* __restrict__ dWhh1,
    const float* __restrict__ dbih1, const float* __restrict__ dbhh1,
    const float* __restrict__ fcW, const float* __restrict__ fcb,
    float* __restrict__ out)
{
    const int tid  = threadIdx.x;
    const int wv   = tid >> 6;          // n-tile owned by this wave (0..3)
    const int lane = tid & 63;
    const int p    = lane & 15;         // A-m / C-col-within-tile
    const int q    = lane >> 4;         // k-quad / C row-quad
    const int col  = wv * 16 + p;       // this lane's hidden-unit column
    const int r0   = blockIdx.x * kM;

    __shared__ __align__(16) _Float16 Hhi1[kM * kStrH];
    __shared__ __align__(16) _Float16 Hhi2[kM * kStrH];
    __shared__ __align__(16) float xbuf[kM * kTH * 2];
    __shared__ __align__(16) float predbuf[kM * kTP * 2];  // preds staged; flushed once

    for (int i = tid; i < kM * kTH * 2; i += 256)
        xbuf[i] = x[r0 * (kTH * 2) + i];

    f16x8 H1f[2], H2f[2];
#pragma unroll
    for (int c = 0; c < 2; ++c) {
        H1f[c] = f16x8{0, 0, 0, 0, 0, 0, 0, 0};
        H2f[c] = f16x8{0, 0, 0, 0, 0, 0, 0, 0};
    }
    __syncthreads();

    const int aoff = p * kStrH;  // A-fragment base for this lane's m-row

    // ================= encoder: 11 steps =================
    {
        const float b0 = ebih0[col] + ebhh0[col];
        const float b1 = ebih1[col] + ebhh1[col];
        const float w0 = eWih0[col * 2 + 0];
        const float w1 = eWih0[col * 2 + 1];
        f16x8 B0[2], B1[2], B2[2];
        loadB1(eWhh0, col, q, B0);   // Whh0
        loadB1(eWih1, col, q, B1);   // Wih1
        loadB1(eWhh1, col, q, B2);   // Whh1

        f32x4 P1 = {b0, b0, b0, b0};       // b0 + Whh0 . h1 (h1 = 0 initially)

#pragma unroll 1
        for (int t = 0; t < kTH; ++t) {
#pragma unroll
            for (int r = 0; r < 4; ++r) {
                const float2 xv = *reinterpret_cast<const float2*>(
                    &xbuf[(4 * q + r) * (kTH * 2) + 2 * t]);
                const float h1 = fast_tanh(fmaf(w0, xv.x, fmaf(w1, xv.y, P1[r])));
                Hhi1[(4 * q + r) * kStrH + col] = (_Float16)h1;
            }
            // layer-2 partial on OLD H2 (independent of h1') before the barrier
            f32x4 a2 = {b1, b1, b1, b1};
#pragma unroll
            for (int c = 0; c < 2; ++c)
                a2 = mfma1(H2f[c], B2[c], a2);
            __syncthreads();   // h1' visible

            // segment A->B: chain-critical a2 finish, produce h2'
#pragma unroll
            for (int c = 0; c < 2; ++c)
                H1f[c] = read_frag(Hhi1, aoff + c * 32 + q * 8);
#pragma unroll
            for (int c = 0; c < 2; ++c)
                a2 = mfma1(H1f[c], B1[c], a2);
#pragma unroll
            for (int r = 0; r < 4; ++r) {
                const float h2 = fast_tanh(a2[r]);
                Hhi2[(4 * q + r) * kStrH + col] = (_Float16)h2;
            }
            __syncthreads();   // h2' visible

            // segment B->A: next-P1 recurrent term (H1 frags still live)
#pragma unroll
            for (int c = 0; c < 2; ++c)
                H2f[c] = read_frag(Hhi2, aoff + c * 32 + q * 8);
            f32x4 np = {b0, b0, b0, b0};
#pragma unroll
            for (int c = 0; c < 2; ++c)
                np = mfma1(H1f[c], B0[c], np);
            P1 = np;
        }
    }

    // ================= decoder: 80 autoregressive steps =================
    {
        const float b0 = dbih0[col] + dbhh0[col];
        const float b1 = dbih1[col] + dbhh1[col];
        const float w0 = dWih0[col * 2 + 0];
        const float w1 = dWih0[col * 2 + 1];
        const float fb0 = fcb[0];
        const float fb1 = fcb[1];
        // folded bias: feedback constant term absorbed into layer-1 bias
        const float b0p = b0 + w0 * fb0 + w1 * fb1;
        const float fbp = (p == 0) ? fb0 : fb1;   // for LDS stash from p<2 lanes
        f16x8 B0[2], B1[2], B2[2], BF[2], BG[2];
        loadB1(dWhh0, col, q, B0);
        loadB1(dWih1, col, q, B1);
        loadB1(dWhh1, col, q, B2);
        loadBfc(fcW, p, q, BF);
        loadBG(fcW, w0, w1, q, BG);   // rank-2 folded feedback matrix

        // P1 for the FIRST decoder step: b0 + Whh0.h1_enc + w0*x_last0 + w1*x_last1
        f32x4 P1 = {b0, b0, b0, b0};
#pragma unroll
        for (int c = 0; c < 2; ++c)
            P1 = mfma1(H1f[c], B0[c], P1);
#pragma unroll
        for (int r = 0; r < 4; ++r) {
            const float2 xv = *reinterpret_cast<const float2*>(
                &xbuf[(4 * q + r) * (kTH * 2) + 2 * (kTH - 1)]);
            P1[r] = fmaf(w0, xv.x, fmaf(w1, xv.y, P1[r]));
        }

#pragma unroll 1
        for (int t = 0; t < kTP; ++t) {
            // layer 1: P1 is already complete (bias + recurrent + folded feedback)
#pragma unroll
            for (int r = 0; r < 4; ++r) {
                const float h1 = fast_tanh(P1[r]);
                Hhi1[(4 * q + r) * kStrH + col] = (_Float16)h1;
            }
            // layer-2 partial on OLD H2 before the barrier
            f32x4 a2 = {b1, b1, b1, b1};
#pragma unroll
            for (int c = 0; c < 2; ++c)
                a2 = mfma1(H2f[c], B2[c], a2);
            __syncthreads();   // h1' visible

            // segment A->B: chain-critical only — finish a2, produce h2'
#pragma unroll
            for (int c = 0; c < 2; ++c)
                H1f[c] = read_frag(Hhi1, aoff + c * 32 + q * 8);
#pragma unroll
            for (int c = 0; c < 2; ++c)
                a2 = mfma1(H1f[c], B1[c], a2);
#pragma unroll
            for (int r = 0; r < 4; ++r) {
                const float h2 = fast_tanh(a2[r]);
                Hhi2[(4 * q + r) * kStrH + col] = (_Float16)h2;
            }
            __syncthreads();   // h2' visible

            // segment B->A: next-P1 assembly + fc (fc on ALL waves: balanced)
#pragma unroll
            for (int c = 0; c < 2; ++c)
                H2f[c] = read_frag(Hhi2, aoff + c * 32 + q * 8);
            f32x4 np = {b0p, b0p, b0p, b0p};
#pragma unroll
            for (int c = 0; c < 2; ++c)
                np = mfma1(H2f[c], BG[c], np);
#pragma unroll
            for (int c = 0; c < 2; ++c)
                np = mfma1(H1f[c], B0[c], np);
            P1 = np;

            f32x4 fcC = {0.f, 0.f, 0.f, 0.f};
#pragma unroll
            for (int c = 0; c < 2; ++c)
                fcC = mfma1(H2f[c], BF[c], fcC);
            if (wv == 0 && p < 2) {
#pragma unroll
                for (int r = 0; r < 4; ++r)
                    predbuf[((4 * q + r) * kTP + t) * 2 + p] = fcC[r] + fbp;
            }
        }
    }

    // flush preds: block covers out[r0*kTP*2 .. (r0+16)*kTP*2), contiguous & aligned
    __syncthreads();
    {
        float4* dst = reinterpret_cast<float4*>(out + r0 * (kTP * 2));
        const float4* src = reinterpret_cast<const float4*>(predbuf);
        for (int i = tid; i < kM * kTP * 2 / 4; i += 256)
            dst[i] = src[i];
    }
}

extern "C" void kernel_launch(void* const* d_in, const int* in_sizes, int n_in,
                              void* d_out, int out_size, void* d_ws, size_t ws_size,
                              hipStream_t stream) {
    const float* x     = (const float*)d_in[0];
    const float* eWih0 = (const float*)d_in[1];
    const float* eWhh0 = (const float*)d_in[2];
    const float* ebih0 = (const float*)d_in[3];
    const float* ebhh0 = (const float*)d_in[4];
    const float* eWih1 = (const float*)d_in[5];
    const float* eWhh1 = (const float*)d_in[6];
    const float* ebih1 = (const float*)d_in[7];
    const float* ebhh1 = (const float*)d_in[8];
    const float* dWih0 = (const float*)d_in[9];
    const float* dWhh0 = (const float*)d_in[10];
    const float* dbih0 = (const float*)d_in[11];
    const float* dbhh0 = (const float*)d_in[12];
    const float* dWih1 = (const float*)d_in[13];
    const float* dWhh1 = (const float*)d_in[14];
    const float* dbih1 = (const float*)d_in[15];
    const float* dbhh1 = (const float*)d_in[16];
    const float* fcW   = (const float*)d_in[17];
    const float* fcb   = (const float*)d_in[18];
    float* out = (float*)d_out;

    dim3 grid(kB / kM);   // 512 blocks x 4 waves; wave n owns output cols 16n..16n+15
    dim3 block(256);
    traj_rnn_kernel<<<grid, block, 0, stream>>>(
        x, eWih0, eWhh0, ebih0, ebhh0, eWih1, eWhh1, ebih1, ebhh1,
        dWih0, dWhh0, dbih0, dbhh0, dWih1, dWhh1, dbih1, dbhh1,
        fcW, fcb, out);
}

// Round 16
// 141.213 us; speedup vs baseline: 1.1948x; 1.0029x over previous
//
#include <hip/hip_runtime.h>

typedef __attribute__((ext_vector_type(8))) _Float16 f16x8;
typedef __attribute__((ext_vector_type(4))) float   f32x4;

namespace {
constexpr int kB    = 8192;
constexpr int kTH   = 11;
constexpr int kTP   = 80;
constexpr int kM    = 16;    // batch rows per block (MFMA M)
constexpr int kStrH = 72;    // H-plane row stride in fp16 units (144 B: 16B-aligned)
}

// 8 fp32 -> fp16x8 (round-to-nearest)
__device__ __forceinline__ f16x8 cvt8(const float* f) {
    f16x8 v;
#pragma unroll
    for (int j = 0; j < 8; ++j) v[j] = (_Float16)f[j];
    return v;
}

// B-fragment (single fp16) for column `col`: B[k][col] = W[col][k].
__device__ __forceinline__ void loadB1(const float* __restrict__ W, int col, int q,
                                       f16x8 (&Bf)[2]) {
#pragma unroll
    for (int c = 0; c < 2; ++c) {
        const float* src = W + col * 64 + c * 32 + q * 8;
        const float4 a = reinterpret_cast<const float4*>(src)[0];
        const float4 b = reinterpret_cast<const float4*>(src)[1];
        float f[8] = {a.x, a.y, a.z, a.w, b.x, b.y, b.z, b.w};
        Bf[c] = cvt8(f);
    }
}

// fc B-fragment: only cols p<2 are real (fcW is 2x64); others zero.
__device__ __forceinline__ void loadBfc(const float* __restrict__ fcW, int p, int q,
                                        f16x8 (&Bf)[2]) {
#pragma unroll
    for (int c = 0; c < 2; ++c) {
        float f[8];
#pragma unroll
        for (int j = 0; j < 8; ++j)
            f[j] = (p < 2) ? fcW[p * 64 + c * 32 + q * 8 + j] : 0.f;
        Bf[c] = cvt8(f);
    }
}

// G = w0 (x) fcW[0] + w1 (x) fcW[1]  (rank-2 folded feedback matrix)
__device__ __forceinline__ void loadBG(const float* __restrict__ fcW, float w0, float w1,
                                       int q, f16x8 (&Bf)[2]) {
#pragma unroll
    for (int c = 0; c < 2; ++c) {
        float f[8];
#pragma unroll
        for (int j = 0; j < 8; ++j) {
            const int k = c * 32 + q * 8 + j;
            f[j] = w0 * fcW[k] + w1 * fcW[64 + k];
        }
        Bf[c] = cvt8(f);
    }
}

__device__ __forceinline__ f16x8 read_frag(const _Float16* plane, int off) {
    return *reinterpret_cast<const f16x8*>(plane + off);
}

// single-term accumulate: D += A*B (A = fp16 h, B = fp16 W)
__device__ __forceinline__ f32x4 mfma1(f16x8 a, f16x8 b, f32x4 acc) {
    return __builtin_amdgcn_mfma_f32_16x16x32_f16(a, b, acc, 0, 0, 0);
}

// tanh via raw v_exp/v_rcp: 1 - 2*rcp(2^(2*log2e*x)+1); saturates safely.
__device__ __forceinline__ float fast_tanh(float x) {
    const float e = __builtin_amdgcn_exp2f(x * 2.8853900817779268f);  // 2/ln2
    return fmaf(-2.0f, __builtin_amdgcn_rcpf(e + 1.0f), 1.0f);
}

// R9 structure: 512 blocks x 4 waves (n-split), 2 waves/SIMD grid-limited.
__global__ __attribute__((amdgpu_waves_per_eu(2, 2))) __launch_bounds__(256)
void traj_rnn_kernel(
    const float* __restrict__ x,
    const float* __restrict__ eWih0, const float* __restrict__ eWhh0,
    const float* __restrict__ ebih0, const float* __restrict__ ebhh0,
    const float* __restrict__ eWih1, const float* __restrict__ eWhh1,
    const float* __restrict__ ebih1, const float* __restrict__ ebhh1,
    const float* __restrict__ dWih0, const float* __restrict__ dWhh0,
    const float* __restrict__ dbih0, const float* __restrict__ dbhh0,
    const float* __restrict__ dWih1, const float* __restrict__ dWhh1,
    const float* __restrict__ dbih1, const float* __restrict__ dbhh1,
    const float* __restrict__ fcW, const float* __restrict__ fcb,
    float* __restrict__ out)
{
    const int tid  = threadIdx.x;
    const int wv   = tid >> 6;          // n-tile owned by this wave (0..3)
    const int lane = tid & 63;
    const int p    = lane & 15;         // A-m / C-col-within-tile
    const int q    = lane >> 4;         // k-quad / C row-quad
    const int col  = wv * 16 + p;       // this lane's hidden-unit column
    const int r0   = blockIdx.x * kM;

    __shared__ __align__(16) _Float16 Hhi1[kM * kStrH];
    __shared__ __align__(16) _Float16 Hhi2[kM * kStrH];
    __shared__ __align__(16) float xbuf[kM * kTH * 2];
    __shared__ __align__(16) float predbuf[kM * kTP * 2];  // preds staged; flushed once

    for (int i = tid; i < kM * kTH * 2; i += 256)
        xbuf[i] = x[r0 * (kTH * 2) + i];

    f16x8 H1f[2], H2f[2];
#pragma unroll
    for (int c = 0; c < 2; ++c) {
        H1f[c] = f16x8{0, 0, 0, 0, 0, 0, 0, 0};
        H2f[c] = f16x8{0, 0, 0, 0, 0, 0, 0, 0};
    }
    __syncthreads();

    const int aoff = p * kStrH;  // A-fragment base for this lane's m-row

    // ================= encoder: 11 steps =================
    {
        const float b0 = ebih0[col] + ebhh0[col];
        const float b1 = ebih1[col] + ebhh1[col];
        const float w0 = eWih0[col * 2 + 0];
        const float w1 = eWih0[col * 2 + 1];
        f16x8 B0[2], B1[2], B2[2];
        loadB1(eWhh0, col, q, B0);   // Whh0
        loadB1(eWih1, col, q, B1);   // Wih1
        loadB1(eWhh1, col, q, B2);   // Whh1

        f32x4 P1 = {b0, b0, b0, b0};       // b0 + Whh0 . h1 (h1 = 0 initially)

#pragma unroll 1
        for (int t = 0; t < kTH; ++t) {
#pragma unroll
            for (int r = 0; r < 4; ++r) {
                const float2 xv = *reinterpret_cast<const float2*>(
                    &xbuf[(4 * q + r) * (kTH * 2) + 2 * t]);
                const float h1 = fast_tanh(fmaf(w0, xv.x, fmaf(w1, xv.y, P1[r])));
                Hhi1[(4 * q + r) * kStrH + col] = (_Float16)h1;
            }
            // layer-2 partial on OLD H2 (independent of h1') before the barrier
            f32x4 a2 = {b1, b1, b1, b1};
#pragma unroll
            for (int c = 0; c < 2; ++c)
                a2 = mfma1(H2f[c], B2[c], a2);
            __syncthreads();   // h1' visible

            // segment A->B: chain-critical a2 finish, produce h2'
#pragma unroll
            for (int c = 0; c < 2; ++c)
                H1f[c] = read_frag(Hhi1, aoff + c * 32 + q * 8);
#pragma unroll
            for (int c = 0; c < 2; ++c)
                a2 = mfma1(H1f[c], B1[c], a2);
#pragma unroll
            for (int r = 0; r < 4; ++r) {
                const float h2 = fast_tanh(a2[r]);
                Hhi2[(4 * q + r) * kStrH + col] = (_Float16)h2;
            }
            __syncthreads();   // h2' visible

            // segment B->A: next-P1 recurrent term (H1 frags still live)
#pragma unroll
            for (int c = 0; c < 2; ++c)
                H2f[c] = read_frag(Hhi2, aoff + c * 32 + q * 8);
            f32x4 np = {b0, b0, b0, b0};
#pragma unroll
            for (int c = 0; c < 2; ++c)
                np = mfma1(H1f[c], B0[c], np);
            P1 = np;
        }
    }

    // ================= decoder: 80 autoregressive steps =================
    {
        const float b0 = dbih0[col] + dbhh0[col];
        const float b1 = dbih1[col] + dbhh1[col];
        const float w0 = dWih0[col * 2 + 0];
        const float w1 = dWih0[col * 2 + 1];
        const float fb0 = fcb[0];
        const float fb1 = fcb[1];
        // folded bias: feedback constant term absorbed into layer-1 bias
        const float b0p = b0 + w0 * fb0 + w1 * fb1;
        const float fbp = (p == 0) ? fb0 : fb1;   // for LDS stash from p<2 lanes
        f16x8 B0[2], B1[2], B2[2], BF[2], BG[2];
        loadB1(dWhh0, col, q, B0);
        loadB1(dWih1, col, q, B1);
        loadB1(dWhh1, col, q, B2);
        loadBfc(fcW, p, q, BF);
        loadBG(fcW, w0, w1, q, BG);   // rank-2 folded feedback matrix

        // P1 for the FIRST decoder step: b0 + Whh0.h1_enc + w0*x_last0 + w1*x_last1
        f32x4 P1 = {b0, b0, b0, b0};
#pragma unroll
        for (int c = 0; c < 2; ++c)
            P1 = mfma1(H1f[c], B0[c], P1);
#pragma unroll
        for (int r = 0; r < 4; ++r) {
            const float2 xv = *reinterpret_cast<const float2*>(
                &xbuf[(4 * q + r) * (kTH * 2) + 2 * (kTH - 1)]);
            P1[r] = fmaf(w0, xv.x, fmaf(w1, xv.y, P1[r]));
        }

#pragma unroll 2
        for (int t = 0; t < kTP; ++t) {
            // layer 1: P1 is already complete (bias + recurrent + folded feedback)
#pragma unroll
            for (int r = 0; r < 4; ++r) {
                const float h1 = fast_tanh(P1[r]);
                Hhi1[(4 * q + r) * kStrH + col] = (_Float16)h1;
            }
            // layer-2 partial on OLD H2 before the barrier
            f32x4 a2 = {b1, b1, b1, b1};
#pragma unroll
            for (int c = 0; c < 2; ++c)
                a2 = mfma1(H2f[c], B2[c], a2);
            __syncthreads();   // h1' visible

            // segment A->B: chain-critical only — finish a2, produce h2'
#pragma unroll
            for (int c = 0; c < 2; ++c)
                H1f[c] = read_frag(Hhi1, aoff + c * 32 + q * 8);
#pragma unroll
            for (int c = 0; c < 2; ++c)
                a2 = mfma1(H1f[c], B1[c], a2);
#pragma unroll
            for (int r = 0; r < 4; ++r) {
                const float h2 = fast_tanh(a2[r]);
                Hhi2[(4 * q + r) * kStrH + col] = (_Float16)h2;
            }
            __syncthreads();   // h2' visible

            // segment B->A: next-P1 as TWO independent 2-chains (G.h2 || B0.h1),
            // merged with one vector add — shortens the np critical path.
#pragma unroll
            for (int c = 0; c < 2; ++c)
                H2f[c] = read_frag(Hhi2, aoff + c * 32 + q * 8);
            f32x4 ng = {b0p, b0p, b0p, b0p};
            f32x4 nb = {0.f, 0.f, 0.f, 0.f};
#pragma unroll
            for (int c = 0; c < 2; ++c) {
                ng = mfma1(H2f[c], BG[c], ng);
                nb = mfma1(H1f[c], B0[c], nb);
            }
            P1 = ng + nb;

            // fc on all waves (balanced); only wave 0 p<2 stores
            f32x4 fcC = {0.f, 0.f, 0.f, 0.f};
#pragma unroll
            for (int c = 0; c < 2; ++c)
                fcC = mfma1(H2f[c], BF[c], fcC);
            if (wv == 0 && p < 2) {
#pragma unroll
                for (int r = 0; r < 4; ++r)
                    predbuf[((4 * q + r) * kTP + t) * 2 + p] = fcC[r] + fbp;
            }
        }
    }

    // flush preds: block covers out[r0*kTP*2 .. (r0+16)*kTP*2), contiguous & aligned
    __syncthreads();
    {
        float4* dst = reinterpret_cast<float4*>(out + r0 * (kTP * 2));
        const float4* src = reinterpret_cast<const float4*>(predbuf);
        for (int i = tid; i < kM * kTP * 2 / 4; i += 256)
            dst[i] = src[i];
    }
}

extern "C" void kernel_launch(void* const* d_in, const int* in_sizes, int n_in,
                              void* d_out, int out_size, void* d_ws, size_t ws_size,
                              hipStream_t stream) {
    const float* x     = (const float*)d_in[0];
    const float* eWih0 = (const float*)d_in[1];
    const float* eWhh0 = (const float*)d_in[2];
    const float* ebih0 = (const float*)d_in[3];
    const float* ebhh0 = (const float*)d_in[4];
    const float* eWih1 = (const float*)d_in[5];
    const float* eWhh1 = (const float*)d_in[6];
    const float* ebih1 = (const float*)d_in[7];
    const float* ebhh1 = (const float*)d_in[8];
    const float* dWih0 = (const float*)d_in[9];
    const float* dWhh0 = (const float*)d_in[10];
    const float* dbih0 = (const float*)d_in[11];
    const float* dbhh0 = (const float*)d_in[12];
    const float* dWih1 = (const float*)d_in[13];
    const float* dWhh1 = (const float*)d_in[14];
    const float* dbih1 = (const float*)d_in[15];
    const float* dbhh1 = (const float*)d_in[16];
    const float* fcW   = (const float*)d_in[17];
    const float* fcb   = (const float*)d_in[18];
    float* out = (float*)d_out;

    dim3 grid(kB / kM);   // 512 blocks x 4 waves; wave n owns output cols 16n..16n+15
    dim3 block(256);
    traj_rnn_kernel<<<grid, block, 0, stream>>>(
        x, eWih0, eWhh0, ebih0, ebhh0, eWih1, eWhh1, ebih1, ebhh1,
        dWih0, dWhh0, dbih0, dbhh0, dWih1, dWhh1, dbih1, dbhh1,
        fcW, fcb, out);
}